// Round 17
// baseline (358.570 us; speedup 1.0000x reference)
//
#include <hip/hip_runtime.h>

typedef unsigned short u16;
typedef __attribute__((ext_vector_type(8))) short short8;
typedef __attribute__((ext_vector_type(4))) float floatx4;
typedef __attribute__((ext_vector_type(16))) float floatx16;

#define MFMA_BF16(a, b, c) __builtin_amdgcn_mfma_f32_16x16x32_bf16((a), (b), (c), 0, 0, 0)
#define MFMA32(a, b, c) __builtin_amdgcn_mfma_f32_32x32x16_bf16((a), (b), (c), 0, 0, 0)

__device__ __forceinline__ u16 f2bf(float f) {
  unsigned b = __float_as_uint(f);
  b = b + 0x7FFFu + ((b >> 16) & 1u);
  return (u16)(b >> 16);
}

// exp(s * 0.125) = 2^(s * 0.125*log2(e)); single mul + raw v_exp_f32
__device__ __forceinline__ float fexp8(float s) {
  float r;
  asm("v_exp_f32 %0, %1" : "=v"(r) : "v"(s * 0.18033688011112042f));
  return r;
}

// pack two f32 -> one u32 of 2x bf16 (lo = a, hi = b)
__device__ __forceinline__ unsigned cvtpk(float a, float b) {
  unsigned r;
  asm("v_cvt_pk_bf16_f32 %0, %1, %2" : "=v"(r) : "v"(a), "v"(b));
  return r;
}

// v_permlane32_swap_b32: x[32:63] <-> y[0:31]
__device__ __forceinline__ void plswap(unsigned& x, unsigned& y) {
  asm("v_permlane32_swap_b32 %0, %1" : "+v"(x), "+v"(y));
}

// async global->LDS, 16B/lane; lds ptr is wave-uniform base, lane i lands at +i*16B
__device__ __forceinline__ void gll16(const u16* g, u16* lds_uniform) {
  __builtin_amdgcn_global_load_lds(
      (const __attribute__((address_space(1))) void*)g,
      (__attribute__((address_space(3))) void*)lds_uniform, 16, 0, 0);
}

// ---------------- fused fp32 -> bf16 cast for all 6 weights + bias concat --
// blocks 0..2047: weight casts; blocks 2048..2053: bcat = bq|bk|bv (1536 f32)
__global__ __launch_bounds__(256) void cast_all_kernel(
    const float* __restrict__ wq, const float* __restrict__ wk,
    const float* __restrict__ wv, const float* __restrict__ wo,
    const float* __restrict__ w1, const float* __restrict__ w2,
    u16* __restrict__ wcat, u16* __restrict__ wob,
    u16* __restrict__ w1b, u16* __restrict__ w2b,
    const float* __restrict__ bq, const float* __restrict__ bk,
    const float* __restrict__ bv, float* __restrict__ bcat) {
  if (blockIdx.x >= 2048) {
    int i = (blockIdx.x - 2048) * 256 + threadIdx.x;  // < 1536
    float v = (i < 512) ? bq[i] : (i < 1024) ? bk[i - 512] : bv[i - 1024];
    bcat[i] = v;
    return;
  }
  int i = blockIdx.x * 256 + threadIdx.x;
  const float4* src;
  ushort4* dst;
  if (i < 196608) {
    src = (const float4*)((i < 65536) ? wq : (i < 131072) ? wk : wv) + (i & 65535);
    dst = (ushort4*)wcat + i;
  } else if (i < 262144) {
    src = (const float4*)wo + (i - 196608);
    dst = (ushort4*)wob + (i - 196608);
  } else if (i < 393216) {
    src = (const float4*)w1 + (i - 262144);
    dst = (ushort4*)w1b + (i - 262144);
  } else {
    src = (const float4*)w2 + (i - 393216);
    dst = (ushort4*)w2b + (i - 393216);
  }
  float4 v = *src;
  ushort4 o;
  o.x = f2bf(v.x); o.y = f2bf(v.y); o.z = f2bf(v.z); o.w = f2bf(v.w);
  *dst = o;
}

// ---------------- LayerNorm (D=512): one 64-lane wave per row -------------
__global__ __launch_bounds__(256) void ln_kernel(const float* __restrict__ x,
                                                 const float* __restrict__ g,
                                                 const float* __restrict__ be,
                                                 u16* __restrict__ y) {
  int wave = threadIdx.x >> 6, lane = threadIdx.x & 63;
  int row = blockIdx.x * 4 + wave;
  const float4* xr = (const float4*)(x + (size_t)row * 512);
  float4 v0 = xr[lane];
  float4 v1 = xr[lane + 64];
  float s = v0.x + v0.y + v0.z + v0.w + v1.x + v1.y + v1.z + v1.w;
  float q = v0.x * v0.x + v0.y * v0.y + v0.z * v0.z + v0.w * v0.w +
            v1.x * v1.x + v1.y * v1.y + v1.z * v1.z + v1.w * v1.w;
#pragma unroll
  for (int off = 32; off > 0; off >>= 1) {
    s += __shfl_xor(s, off);
    q += __shfl_xor(q, off);
  }
  float mu = s * (1.0f / 512.0f);
  float var = q * (1.0f / 512.0f) - mu * mu;
  float rs = rsqrtf(var + 1e-5f);
  float4 g0 = ((const float4*)g)[lane];
  float4 g1 = ((const float4*)g)[lane + 64];
  float4 b0 = ((const float4*)be)[lane];
  float4 b1 = ((const float4*)be)[lane + 64];
  ushort4 o0, o1;
  o0.x = f2bf((v0.x - mu) * rs * g0.x + b0.x);
  o0.y = f2bf((v0.y - mu) * rs * g0.y + b0.y);
  o0.z = f2bf((v0.z - mu) * rs * g0.z + b0.z);
  o0.w = f2bf((v0.w - mu) * rs * g0.w + b0.w);
  o1.x = f2bf((v1.x - mu) * rs * g1.x + b1.x);
  o1.y = f2bf((v1.y - mu) * rs * g1.y + b1.y);
  o1.z = f2bf((v1.z - mu) * rs * g1.z + b1.z);
  o1.w = f2bf((v1.w - mu) * rs * g1.w + b1.w);
  ushort4* yr = (ushort4*)(y + (size_t)row * 512);
  yr[lane] = o0;
  yr[lane + 64] = o1;
}

// ---------------- m97-style MFMA GEMM, BK=64, 4 blocks/CU (128x128) ------
// VSPLIT (qkv only): V col-blocks store straight to vT via LDS retile
// (absorbs the old vtrans kernel). See r16 notes.
template <bool OUTB, bool SILU, bool RES, bool VSPLIT>
__global__ __launch_bounds__(256, 4) void gemm_bt_kernel(
    const u16* __restrict__ A, const u16* __restrict__ W,
    const float* __restrict__ bias, const float* __restrict__ res,
    void* __restrict__ out, u16* __restrict__ vTp, int N, int K, int nx) {
  constexpr int SHSZ = VSPLIT ? 17408 : 16384;  // u16 units
  __shared__ __align__(16) u16 SH[SHSZ];
  u16* As = SH;
  u16* Bs = SH + 8192;
  int t = threadIdx.x;
  int lane = t & 63, wave = t >> 6;
  int l15 = lane & 15, quad = lane >> 4;
  int nblk = gridDim.x;
  int L = (blockIdx.x & 7) * (nblk >> 3) + (blockIdx.x >> 3);
  int rowBlk = (L / nx) * 128, colBlk = (L % nx) * 128;
  const u16* Ag = A + (size_t)(rowBlk + (t >> 2)) * K + (t & 3) * 8;
  const u16* Wg = W + (size_t)(colBlk + (t >> 2)) * K + (t & 3) * 8;
  u16* AsW = As + wave * 512;
  u16* BsW = Bs + wave * 512;
  int arow = (wave >> 1) * 64;
  int brow = (wave & 1) * 64;
  floatx4 acc[4][4] = {};
  for (int k0 = 0; k0 < K; k0 += 64) {
    gll16(Ag + k0, AsW);
    gll16(Ag + (size_t)64 * K + k0, AsW + 2048);
    gll16(Ag + k0 + 32, AsW + 4096);
    gll16(Ag + (size_t)64 * K + k0 + 32, AsW + 6144);
    gll16(Wg + k0, BsW);
    gll16(Wg + (size_t)64 * K + k0, BsW + 2048);
    gll16(Wg + k0 + 32, BsW + 4096);
    gll16(Wg + (size_t)64 * K + k0 + 32, BsW + 6144);
    __syncthreads();
#pragma unroll 1
    for (int kk = 0; kk < 2; ++kk) {
      short8 a[4], b[4];
#pragma unroll
      for (int i = 0; i < 4; ++i)
        a[i] = *(const short8*)(As + kk * 4096 +
                                (size_t)(arow + i * 16 + l15) * 32 + quad * 8);
#pragma unroll
      for (int j = 0; j < 4; ++j)
        b[j] = *(const short8*)(Bs + kk * 4096 +
                                (size_t)(brow + j * 16 + l15) * 32 + quad * 8);
#pragma unroll
      for (int i = 0; i < 4; ++i)
#pragma unroll
        for (int j = 0; j < 4; ++j)
          acc[i][j] = MFMA_BF16(a[i], b[j], acc[i][j]);
    }
    __syncthreads();
  }
  if (VSPLIT && colBlk >= 1024) {
    // ---- V block: retile through LDS (transposed), store coalesced to vT
    u16* TL = SH;  // [col 0..127][136], 34KB; As/Bs dead past last barrier
#pragma unroll
    for (int j = 0; j < 4; ++j) {
      int colL = brow + j * 16 + l15;
      float bs = bias[colBlk + colL];
#pragma unroll
      for (int i = 0; i < 4; ++i) {
        int rowL = arow + i * 16 + quad * 4;
        ushort4 o;
        o.x = f2bf(acc[i][j][0] + bs);
        o.y = f2bf(acc[i][j][1] + bs);
        o.z = f2bf(acc[i][j][2] + bs);
        o.w = f2bf(acc[i][j][3] + bs);
        *(ushort4*)(TL + colL * 136 + rowL) = o;
      }
    }
    __syncthreads();
    int bb = rowBlk >> 10, n0 = rowBlk & 1023;
    int c0 = colBlk - 1024;
#pragma unroll
    for (int rep = 0; rep < 8; ++rep) {
      int id = rep * 256 + t;            // 0..2047
      int c = id >> 4, n8 = (id & 15) * 8;
      short8 v = *(const short8*)(TL + c * 136 + n8);
      int ch = c0 + c;
      *(short8*)(vTp + ((size_t)(bb * 8 + (ch >> 6)) * 64 + (ch & 63)) * 1024 +
                 n0 + n8) = v;
    }
    return;
  }
#pragma unroll
  for (int j = 0; j < 4; ++j) {
    int col = colBlk + brow + j * 16 + l15;
    float bs = bias[col];
#pragma unroll
    for (int i = 0; i < 4; ++i) {
      int row0 = rowBlk + arow + i * 16 + quad * 4;
#pragma unroll
      for (int r = 0; r < 4; ++r) {
        size_t idx = (size_t)(row0 + r) * N + col;
        float v = acc[i][j][r] + bs;
        if (RES) v += res[idx];
        if (SILU) v = v * (1.0f / (1.0f + __expf(-v)));
        if (OUTB) ((u16*)out)[idx] = f2bf(v);
        else ((float*)out)[idx] = v;
      }
    }
  }
}

// ---------------- 64x128-tile GEMM variant for small-grid shapes ----------
template <bool OUTB, bool SILU, bool RES>
__global__ __launch_bounds__(256, 4) void gemm_bt64_kernel(
    const u16* __restrict__ A, const u16* __restrict__ W,
    const float* __restrict__ bias, const float* __restrict__ res,
    void* __restrict__ out, int N, int K, int nx) {
  __shared__ __align__(16) u16 As[2 * 64 * 32];   // 8KB
  __shared__ __align__(16) u16 Bs[2 * 128 * 32];  // 16KB
  int t = threadIdx.x;
  int lane = t & 63, wave = t >> 6;
  int l15 = lane & 15, quad = lane >> 4;
  int nblk = gridDim.x;
  int L = (blockIdx.x & 7) * (nblk >> 3) + (blockIdx.x >> 3);
  int rowBlk = (L / nx) * 64, colBlk = (L % nx) * 128;
  const u16* Ag = A + (size_t)(rowBlk + (t >> 2)) * K + (t & 3) * 8;
  const u16* Wg = W + (size_t)(colBlk + (t >> 2)) * K + (t & 3) * 8;
  u16* AsW = As + wave * 512;
  u16* BsW = Bs + wave * 512;
  int brow = wave * 32;
  floatx4 acc[4][2] = {};
  for (int k0 = 0; k0 < K; k0 += 64) {
    gll16(Ag + k0, AsW);
    gll16(Ag + k0 + 32, AsW + 2048);
    gll16(Wg + k0, BsW);
    gll16(Wg + (size_t)64 * K + k0, BsW + 2048);
    gll16(Wg + k0 + 32, BsW + 4096);
    gll16(Wg + (size_t)64 * K + k0 + 32, BsW + 6144);
    __syncthreads();
#pragma unroll 1
    for (int kk = 0; kk < 2; ++kk) {
      short8 a[4], b[2];
#pragma unroll
      for (int i = 0; i < 4; ++i)
        a[i] = *(const short8*)(As + kk * 2048 +
                                (size_t)(i * 16 + l15) * 32 + quad * 8);
#pragma unroll
      for (int j = 0; j < 2; ++j)
        b[j] = *(const short8*)(Bs + kk * 4096 +
                                (size_t)(brow + j * 16 + l15) * 32 + quad * 8);
#pragma unroll
      for (int i = 0; i < 4; ++i)
#pragma unroll
        for (int j = 0; j < 2; ++j)
          acc[i][j] = MFMA_BF16(a[i], b[j], acc[i][j]);
    }
    __syncthreads();
  }
#pragma unroll
  for (int j = 0; j < 2; ++j) {
    int col = colBlk + brow + j * 16 + l15;
    float bs = bias[col];
#pragma unroll
    for (int i = 0; i < 4; ++i) {
      int row0 = rowBlk + i * 16 + quad * 4;
#pragma unroll
      for (int r = 0; r < 4; ++r) {
        size_t idx = (size_t)(row0 + r) * N + col;
        float v = acc[i][j][r] + bs;
        if (RES) v += res[idx];
        if (SILU) v = v * (1.0f / (1.0f + __expf(-v)));
        if (OUTB) ((u16*)out)[idx] = f2bf(v);
        else ((float*)out)[idx] = v;
      }
    }
  }
}

// ---------------- attention ctx v2 + T5 setprio around MFMA clusters ------
__global__ __launch_bounds__(256, 4) void attn_ctx_kernel(const u16* __restrict__ qkv,
                                                          const u16* __restrict__ vT,
                                                          u16* __restrict__ ctx,
                                                          float* __restrict__ linv_g) {
  __shared__ __align__(16) u16 Kb[2][4096];  // [key][slot8] swizzled, 8KB
  __shared__ __align__(16) u16 Vb[2][4096];  // [dh ][slot8] swizzled, 8KB
  int t = threadIdx.x, lane = t & 63, wave = t >> 6;
  int l31 = lane & 31, hi = lane >> 5;
  int li = lane >> 3, sl = lane & 7;  // staging: row r0+li, slot sl
  int bid = blockIdx.x;
  int L = (bid & 7) * 128 + (bid >> 3);
  int qblk = L & 7, h = (L >> 3) & 7, b = L >> 6;
  int q0w = qblk * 128 + wave * 32;

  short8 qf[4];
  const u16* qbase = qkv + (size_t)(b * 1024 + q0w + l31) * 1536 + h * 64;
#pragma unroll
  for (int t4 = 0; t4 < 4; ++t4)
    qf[t4] = *(const short8*)(qbase + t4 * 16 + hi * 8);

  short8 ones;
#pragma unroll
  for (int i = 0; i < 8; ++i) ones[i] = (short)0x3F80;  // bf16 1.0

  floatx16 oacc[2] = {};
  floatx16 psum = {};

  const u16* ksec = qkv + (size_t)(b * 1024) * 1536 + 512 + h * 64;  // + key*1536
  const u16* vsec = vT + ((size_t)(b * 8 + h) * 64) * 1024;          // + dh*1024

  auto stageKV = [&](int c, u16* kbuf, u16* vbuf) {
#pragma unroll
    for (int j = 0; j < 2; ++j) {
      int r0 = wave * 16 + j * 8;
      int row = r0 + li;
      gll16(ksec + (size_t)(c * 64 + row) * 1536 + ((sl ^ (row & 7)) << 3),
            kbuf + r0 * 64);
      gll16(vsec + (size_t)row * 1024 + c * 64 + ((sl ^ (row & 7)) << 3),
            vbuf + r0 * 64);
    }
  };

  stageKV(0, Kb[0], Vb[0]);
  __syncthreads();

#pragma unroll 1
  for (int c = 0; c < 16; ++c) {
    int bf = c & 1;
    if (c < 15) stageKV(c + 1, Kb[bf ^ 1], Vb[bf ^ 1]);
    short8 pa[4];
#pragma unroll
    for (int ct = 0; ct < 2; ++ct) {
      floatx16 s = {};
      __builtin_amdgcn_s_setprio(1);
#pragma unroll
      for (int t4 = 0; t4 < 4; ++t4) {
        int key = ct * 32 + l31;
        int g2 = t4 * 2 + hi;
        short8 kf = *(const short8*)&Kb[bf][key * 64 + ((g2 ^ (key & 7)) << 3)];
        s = MFMA32(kf, qf[t4], s);
      }
      __builtin_amdgcn_s_setprio(0);
#pragma unroll
      for (int r = 0; r < 16; ++r) s[r] = fexp8(s[r]);
#pragma unroll
      for (int j = 0; j < 2; ++j) {
        unsigned a0 = cvtpk(s[j * 8 + 0], s[j * 8 + 1]);
        unsigned b0 = cvtpk(s[j * 8 + 4], s[j * 8 + 5]);
        unsigned a1 = cvtpk(s[j * 8 + 2], s[j * 8 + 3]);
        unsigned b1 = cvtpk(s[j * 8 + 6], s[j * 8 + 7]);
        plswap(a0, b0);
        plswap(a1, b1);
        union { unsigned u[4]; short8 v8; } uu;
        uu.u[0] = a0; uu.u[1] = a1; uu.u[2] = b0; uu.u[3] = b1;
        pa[ct * 2 + j] = uu.v8;
      }
    }
    __builtin_amdgcn_s_setprio(1);
#pragma unroll
    for (int ks = 0; ks < 4; ++ks) {
      psum = MFMA32(pa[ks], ones, psum);  // rowsum in oacc layout
#pragma unroll
      for (int ct2 = 0; ct2 < 2; ++ct2) {
        int dh = ct2 * 32 + l31;
        int kg = ks * 2 + hi;
        short8 vf = *(const short8*)&Vb[bf][dh * 64 + ((kg ^ (dh & 7)) << 3)];
        oacc[ct2] = MFMA32(pa[ks], vf, oacc[ct2]);
      }
    }
    __builtin_amdgcn_s_setprio(0);
    __syncthreads();
  }

  float il[16];
#pragma unroll
  for (int r = 0; r < 16; ++r) il[r] = 1.0f / psum[r];
  if (l31 == 0) {
#pragma unroll
    for (int reg = 0; reg < 16; ++reg) {
      int row = (reg & 3) + 8 * (reg >> 2) + 4 * hi;
      linv_g[(size_t)(b * 8 + h) * 1024 + q0w + row] = il[reg];
    }
  }
#pragma unroll
  for (int ct = 0; ct < 2; ++ct)
#pragma unroll
    for (int reg = 0; reg < 16; ++reg) {
      int row = (reg & 3) + 8 * (reg >> 2) + 4 * hi;
      ctx[(size_t)(b * 1024 + q0w + row) * 512 + h * 64 + ct * 32 + l31] =
          f2bf(oacc[ct][reg] * il[reg]);
    }
}

// ---------------- averaged attention weights v8 + T5 setprio --------------
__global__ __launch_bounds__(256, 4) void attn_avg_kernel(const u16* __restrict__ qkv,
                                                          const float* __restrict__ linv_g,
                                                          float* __restrict__ attnw) {
  __shared__ __align__(16) u16 Qs[128 * 64];  // [qrow][slot8x u16] 16KB
  __shared__ __align__(16) u16 Ks[64 * 64];   // [key ][slot8x u16]  8KB
  int t = threadIdx.x, lane = t & 63, wave = t >> 6;
  int l31 = lane & 31, hi = lane >> 5;
  int bid = blockIdx.x;
  // 2048 blocks; XCD k (= bid%8) owns L in [256k, 256k+256) = batches {2k,2k+1}
  int L = (bid & 7) * 256 + (bid >> 3);
  int b = L >> 7;
  int r7 = L & 127;
  int kq = r7 & 15, qb = r7 >> 4;
  int q0 = qb * 128;
  int q0w = q0 + wave * 32;
  int key0 = kq * 64;

  int li = lane >> 3, sl = lane & 7;  // staging: lane covers row r0+li, slot sl

  floatx16 acc0 = {}, acc1 = {};

#pragma unroll 1
  for (int h = 0; h < 8; ++h) {
    // ---- stage Q[h] (16 gll16, 4/wave) and K[h] (8 gll16, 2/wave), coalesced
    {
      const u16* qsec = qkv + (size_t)(b * 1024 + q0) * 1536 + h * 64;
#pragma unroll
      for (int j = 0; j < 4; ++j) {
        int r0 = wave * 32 + j * 8;
        int row = r0 + li;
        gll16(qsec + (size_t)row * 1536 + ((sl ^ (row & 7)) << 3), Qs + r0 * 64);
      }
      const u16* ksec = qkv + (size_t)(b * 1024 + key0) * 1536 + 512 + h * 64;
#pragma unroll
      for (int j = 0; j < 2; ++j) {
        int r0 = wave * 16 + j * 8;
        int row = r0 + li;
        gll16(ksec + (size_t)row * 1536 + ((sl ^ (row & 7)) << 3), Ks + r0 * 64);
      }
    }
    __syncthreads();  // staged data landed (vmcnt drain folded into barrier)

    // linv: broadcast loads (uniform over l31, 2 lines/instr)
    const float* lg = linv_g + (size_t)(b * 8 + h) * 1024 + q0w + 4 * hi;
    float4 il0 = *(const float4*)(lg);
    float4 il1 = *(const float4*)(lg + 8);
    float4 il2 = *(const float4*)(lg + 16);
    float4 il3 = *(const float4*)(lg + 24);
    float il[16] = {il0.x, il0.y, il0.z, il0.w, il1.x, il1.y, il1.z, il1.w,
                    il2.x, il2.y, il2.z, il2.w, il3.x, il3.y, il3.z, il3.w};

    // Q fragments from LDS (swizzled read)
    short8 qf[4];
#pragma unroll
    for (int t4 = 0; t4 < 4; ++t4) {
      int row = wave * 32 + l31;
      int g2 = t4 * 2 + hi;
      qf[t4] = *(const short8*)(Qs + row * 64 + ((g2 ^ (row & 7)) << 3));
    }
#pragma unroll
    for (int ct = 0; ct < 2; ++ct) {
      floatx16 sacc = {};
      __builtin_amdgcn_s_setprio(1);
#pragma unroll
      for (int t4 = 0; t4 < 4; ++t4) {
        int key = ct * 32 + l31;
        int g2 = t4 * 2 + hi;
        short8 kf = *(const short8*)(Ks + key * 64 + ((g2 ^ (key & 7)) << 3));
        sacc = MFMA32(qf[t4], kf, sacc);
      }
      __builtin_amdgcn_s_setprio(0);
      if (ct == 0) {
#pragma unroll
        for (int r = 0; r < 16; ++r) acc0[r] += fexp8(sacc[r]) * il[r];
      } else {
#pragma unroll
        for (int r = 0; r < 16; ++r) acc1[r] += fexp8(sacc[r]) * il[r];
      }
    }
    __syncthreads();  // all waves done reading before next h restage
  }

#pragma unroll
  for (int r = 0; r < 16; ++r) {
    int row = (r & 3) + 8 * (r >> 2) + 4 * hi;
    float* dst = &attnw[(size_t)(b * 1024 + q0w + row) * 1024 + key0 + l31];
    __builtin_nontemporal_store(acc0[r] * 0.125f, dst);
    __builtin_nontemporal_store(acc1[r] * 0.125f, dst + 32);
  }
}

// ---------------- host launch ----------------
extern "C" void kernel_launch(void* const* d_in, const int* in_sizes, int n_in,
                              void* d_out, int out_size, void* d_ws, size_t ws_size,
                              hipStream_t stream) {
  (void)in_sizes; (void)n_in; (void)out_size; (void)ws_size;
  const float* h   = (const float*)d_in[0];
  const float* g1  = (const float*)d_in[1];
  const float* be1 = (const float*)d_in[2];
  const float* wq  = (const float*)d_in[3];
  const float* bq  = (const float*)d_in[4];
  const float* wk  = (const float*)d_in[5];
  const float* bk  = (const float*)d_in[6];
  const float* wv  = (const float*)d_in[7];
  const float* bv  = (const float*)d_in[8];
  const float* wo  = (const float*)d_in[9];
  const float* bo  = (const float*)d_in[10];
  const float* g2  = (const float*)d_in[11];
  const float* be2 = (const float*)d_in[12];
  const float* w1  = (const float*)d_in[13];
  const float* b1  = (const float*)d_in[14];
  const float* w2  = (const float*)d_in[15];
  const float* b2  = (const float*)d_in[16];

  char* p = (char*)d_ws;
  auto carve = [&](size_t bytes) {
    char* r = p;
    p += (bytes + 255) & ~(size_t)255;
    return r;
  };
  u16*   wcat = (u16*)carve((size_t)1536 * 512 * 2);
  u16*   wob  = (u16*)carve((size_t)512 * 512 * 2);
  u16*   w1b  = (u16*)carve((size_t)1024 * 512 * 2);
  u16*   w2b  = (u16*)carve((size_t)512 * 1024 * 2);
  float* bcat = (float*)carve((size_t)1536 * 4);
  u16*   hn   = (u16*)carve((size_t)16384 * 512 * 2);
  u16*   qkvb = (u16*)carve((size_t)16384 * 1536 * 2);
  u16*   vTb  = (u16*)carve((size_t)16384 * 512 * 2);
  u16*   ctxb = (u16*)carve((size_t)16384 * 512 * 2);
  u16*   fb   = (u16*)carve((size_t)16384 * 512 * 2);
  u16*   gb   = (u16*)carve((size_t)16384 * 1024 * 2);
  float* linv = (float*)carve((size_t)16 * 8 * 1024 * 4);

  float* outh = (float*)d_out;
  float* outattn = outh + (size_t)16384 * 512;

  cast_all_kernel<<<2054, 256, 0, stream>>>(wq, wk, wv, wo, w1, w2,
                                            wcat, wob, w1b, w2b,
                                            bq, bk, bv, bcat);

  ln_kernel<<<4096, 256, 0, stream>>>(h, g1, be1, hn);
  gemm_bt_kernel<true, false, false, true><<<1536, 256, 0, stream>>>(
      hn, wcat, bcat, nullptr, qkvb, vTb, 1536, 512, 12);
  attn_ctx_kernel<<<1024, 256, 0, stream>>>(qkvb, vTb, ctxb, linv);
  attn_avg_kernel<<<2048, 256, 0, stream>>>(qkvb, linv, outattn);
  gemm_bt64_kernel<false, false, true><<<1024, 256, 0, stream>>>(
      ctxb, wob, bo, h, outh, 512, 512, 4);
  ln_kernel<<<4096, 256, 0, stream>>>(outh, g2, be2, fb);
  gemm_bt_kernel<true, true, false, false><<<1024, 256, 0, stream>>>(
      fb, w1b, b1, nullptr, gb, nullptr, 1024, 512, 8);
  gemm_bt64_kernel<false, false, true><<<1024, 256, 0, stream>>>(
      gb, w2b, b2, outh, outh, 512, 1024, 4);
}

// Round 18
// 355.354 us; speedup vs baseline: 1.0090x; 1.0090x over previous
//
#include <hip/hip_runtime.h>

typedef unsigned short u16;
typedef __attribute__((ext_vector_type(8))) short short8;
typedef __attribute__((ext_vector_type(4))) float floatx4;
typedef __attribute__((ext_vector_type(16))) float floatx16;

#define MFMA_BF16(a, b, c) __builtin_amdgcn_mfma_f32_16x16x32_bf16((a), (b), (c), 0, 0, 0)
#define MFMA32(a, b, c) __builtin_amdgcn_mfma_f32_32x32x16_bf16((a), (b), (c), 0, 0, 0)

__device__ __forceinline__ u16 f2bf(float f) {
  unsigned b = __float_as_uint(f);
  b = b + 0x7FFFu + ((b >> 16) & 1u);
  return (u16)(b >> 16);
}

// exp(s * 0.125) = 2^(s * 0.125*log2(e)); single mul + raw v_exp_f32
__device__ __forceinline__ float fexp8(float s) {
  float r;
  asm("v_exp_f32 %0, %1" : "=v"(r) : "v"(s * 0.18033688011112042f));
  return r;
}

// pack two f32 -> one u32 of 2x bf16 (lo = a, hi = b)
__device__ __forceinline__ unsigned cvtpk(float a, float b) {
  unsigned r;
  asm("v_cvt_pk_bf16_f32 %0, %1, %2" : "=v"(r) : "v"(a), "v"(b));
  return r;
}

// v_permlane32_swap_b32: x[32:63] <-> y[0:31]
__device__ __forceinline__ void plswap(unsigned& x, unsigned& y) {
  asm("v_permlane32_swap_b32 %0, %1" : "+v"(x), "+v"(y));
}

// async global->LDS, 16B/lane; lds ptr is wave-uniform base, lane i lands at +i*16B
__device__ __forceinline__ void gll16(const u16* g, u16* lds_uniform) {
  __builtin_amdgcn_global_load_lds(
      (const __attribute__((address_space(1))) void*)g,
      (__attribute__((address_space(3))) void*)lds_uniform, 16, 0, 0);
}

// ---------------- fused fp32 -> bf16 cast for all 6 weights ----------------
__global__ __launch_bounds__(256) void cast_all_kernel(
    const float* __restrict__ wq, const float* __restrict__ wk,
    const float* __restrict__ wv, const float* __restrict__ wo,
    const float* __restrict__ w1, const float* __restrict__ w2,
    u16* __restrict__ wcat, u16* __restrict__ wob,
    u16* __restrict__ w1b, u16* __restrict__ w2b) {
  int i = blockIdx.x * 256 + threadIdx.x;
  const float4* src;
  ushort4* dst;
  if (i < 196608) {
    src = (const float4*)((i < 65536) ? wq : (i < 131072) ? wk : wv) + (i & 65535);
    dst = (ushort4*)wcat + i;
  } else if (i < 262144) {
    src = (const float4*)wo + (i - 196608);
    dst = (ushort4*)wob + (i - 196608);
  } else if (i < 393216) {
    src = (const float4*)w1 + (i - 262144);
    dst = (ushort4*)w1b + (i - 262144);
  } else {
    src = (const float4*)w2 + (i - 393216);
    dst = (ushort4*)w2b + (i - 393216);
  }
  float4 v = *src;
  ushort4 o;
  o.x = f2bf(v.x); o.y = f2bf(v.y); o.z = f2bf(v.z); o.w = f2bf(v.w);
  *dst = o;
}

// ---------------- fused bias concat (bq|bk|bv -> bcat) ----------------
__global__ __launch_bounds__(256) void bias_cat_kernel(const float* __restrict__ bq,
                                                       const float* __restrict__ bk,
                                                       const float* __restrict__ bv,
                                                       float* __restrict__ bcat) {
  int i = blockIdx.x * 256 + threadIdx.x;  // grid 6*256 = 1536
  float v = (i < 512) ? bq[i] : (i < 1024) ? bk[i - 512] : bv[i - 1024];
  bcat[i] = v;
}

// ---------------- LayerNorm (D=512): one 64-lane wave per row -------------
__global__ __launch_bounds__(256) void ln_kernel(const float* __restrict__ x,
                                                 const float* __restrict__ g,
                                                 const float* __restrict__ be,
                                                 u16* __restrict__ y) {
  int wave = threadIdx.x >> 6, lane = threadIdx.x & 63;
  int row = blockIdx.x * 4 + wave;
  const float4* xr = (const float4*)(x + (size_t)row * 512);
  float4 v0 = xr[lane];
  float4 v1 = xr[lane + 64];
  float s = v0.x + v0.y + v0.z + v0.w + v1.x + v1.y + v1.z + v1.w;
  float q = v0.x * v0.x + v0.y * v0.y + v0.z * v0.z + v0.w * v0.w +
            v1.x * v1.x + v1.y * v1.y + v1.z * v1.z + v1.w * v1.w;
#pragma unroll
  for (int off = 32; off > 0; off >>= 1) {
    s += __shfl_xor(s, off);
    q += __shfl_xor(q, off);
  }
  float mu = s * (1.0f / 512.0f);
  float var = q * (1.0f / 512.0f) - mu * mu;
  float rs = rsqrtf(var + 1e-5f);
  float4 g0 = ((const float4*)g)[lane];
  float4 g1 = ((const float4*)g)[lane + 64];
  float4 b0 = ((const float4*)be)[lane];
  float4 b1 = ((const float4*)be)[lane + 64];
  ushort4 o0, o1;
  o0.x = f2bf((v0.x - mu) * rs * g0.x + b0.x);
  o0.y = f2bf((v0.y - mu) * rs * g0.y + b0.y);
  o0.z = f2bf((v0.z - mu) * rs * g0.z + b0.z);
  o0.w = f2bf((v0.w - mu) * rs * g0.w + b0.w);
  o1.x = f2bf((v1.x - mu) * rs * g1.x + b1.x);
  o1.y = f2bf((v1.y - mu) * rs * g1.y + b1.y);
  o1.z = f2bf((v1.z - mu) * rs * g1.z + b1.z);
  o1.w = f2bf((v1.w - mu) * rs * g1.w + b1.w);
  ushort4* yr = (ushort4*)(y + (size_t)row * 512);
  yr[lane] = o0;
  yr[lane + 64] = o1;
}

// ---------------- m97-style MFMA GEMM, BK=64, 4 blocks/CU (128x128) ------
// VSPLIT (qkv only): V col-blocks (colBlk>=1024) skip the qkvb store and
// instead retile acc through LDS (reusing the dead As/Bs space, TRANSPOSED
// layout TL[col][136] so phase1 = ushort4 writes down r, phase2 = b128 row
// reads) and store straight to vT [b][h][dh][n] fully coalesced. This
// absorbs the former vtrans kernel (saves its 16MB read + 16MB write + the
// qkvb V-section 16MB write + one dispatch). LDS 32->34KB only for VSPLIT
// (4 x 34 = 136KB <= 160 -> still 4 blocks/CU).
template <bool OUTB, bool SILU, bool RES, bool VSPLIT>
__global__ __launch_bounds__(256, 4) void gemm_bt_kernel(
    const u16* __restrict__ A, const u16* __restrict__ W,
    const float* __restrict__ bias, const float* __restrict__ res,
    void* __restrict__ out, u16* __restrict__ vTp, int N, int K, int nx) {
  constexpr int SHSZ = VSPLIT ? 17408 : 16384;  // u16 units
  __shared__ __align__(16) u16 SH[SHSZ];
  u16* As = SH;
  u16* Bs = SH + 8192;
  int t = threadIdx.x;
  int lane = t & 63, wave = t >> 6;
  int l15 = lane & 15, quad = lane >> 4;
  int nblk = gridDim.x;
  int L = (blockIdx.x & 7) * (nblk >> 3) + (blockIdx.x >> 3);
  int rowBlk = (L / nx) * 128, colBlk = (L % nx) * 128;
  const u16* Ag = A + (size_t)(rowBlk + (t >> 2)) * K + (t & 3) * 8;
  const u16* Wg = W + (size_t)(colBlk + (t >> 2)) * K + (t & 3) * 8;
  u16* AsW = As + wave * 512;
  u16* BsW = Bs + wave * 512;
  int arow = (wave >> 1) * 64;
  int brow = (wave & 1) * 64;
  floatx4 acc[4][4] = {};
  for (int k0 = 0; k0 < K; k0 += 64) {
    gll16(Ag + k0, AsW);
    gll16(Ag + (size_t)64 * K + k0, AsW + 2048);
    gll16(Ag + k0 + 32, AsW + 4096);
    gll16(Ag + (size_t)64 * K + k0 + 32, AsW + 6144);
    gll16(Wg + k0, BsW);
    gll16(Wg + (size_t)64 * K + k0, BsW + 2048);
    gll16(Wg + k0 + 32, BsW + 4096);
    gll16(Wg + (size_t)64 * K + k0 + 32, BsW + 6144);
    __syncthreads();
#pragma unroll 1
    for (int kk = 0; kk < 2; ++kk) {
      short8 a[4], b[4];
#pragma unroll
      for (int i = 0; i < 4; ++i)
        a[i] = *(const short8*)(As + kk * 4096 +
                                (size_t)(arow + i * 16 + l15) * 32 + quad * 8);
#pragma unroll
      for (int j = 0; j < 4; ++j)
        b[j] = *(const short8*)(Bs + kk * 4096 +
                                (size_t)(brow + j * 16 + l15) * 32 + quad * 8);
#pragma unroll
      for (int i = 0; i < 4; ++i)
#pragma unroll
        for (int j = 0; j < 4; ++j)
          acc[i][j] = MFMA_BF16(a[i], b[j], acc[i][j]);
    }
    __syncthreads();
  }
  if (VSPLIT && colBlk >= 1024) {
    // ---- V block: retile through LDS (transposed), store coalesced to vT
    u16* TL = SH;  // [col 0..127][136], 34KB; As/Bs are dead past last barrier
#pragma unroll
    for (int j = 0; j < 4; ++j) {
      int colL = brow + j * 16 + l15;
      float bs = bias[colBlk + colL];
#pragma unroll
      for (int i = 0; i < 4; ++i) {
        int rowL = arow + i * 16 + quad * 4;
        ushort4 o;
        o.x = f2bf(acc[i][j][0] + bs);
        o.y = f2bf(acc[i][j][1] + bs);
        o.z = f2bf(acc[i][j][2] + bs);
        o.w = f2bf(acc[i][j][3] + bs);
        *(ushort4*)(TL + colL * 136 + rowL) = o;
      }
    }
    __syncthreads();
    int bb = rowBlk >> 10, n0 = rowBlk & 1023;
    int c0 = colBlk - 1024;
#pragma unroll
    for (int rep = 0; rep < 8; ++rep) {
      int id = rep * 256 + t;            // 0..2047
      int c = id >> 4, n8 = (id & 15) * 8;
      short8 v = *(const short8*)(TL + c * 136 + n8);
      int ch = c0 + c;
      *(short8*)(vTp + ((size_t)(bb * 8 + (ch >> 6)) * 64 + (ch & 63)) * 1024 +
                 n0 + n8) = v;
    }
    return;
  }
#pragma unroll
  for (int j = 0; j < 4; ++j) {
    int col = colBlk + brow + j * 16 + l15;
    float bs = bias[col];
#pragma unroll
    for (int i = 0; i < 4; ++i) {
      int row0 = rowBlk + arow + i * 16 + quad * 4;
#pragma unroll
      for (int r = 0; r < 4; ++r) {
        size_t idx = (size_t)(row0 + r) * N + col;
        float v = acc[i][j][r] + bs;
        if (RES) v += res[idx];
        if (SILU) v = v * (1.0f / (1.0f + __expf(-v)));
        if (OUTB) ((u16*)out)[idx] = f2bf(v);
        else ((float*)out)[idx] = v;
      }
    }
  }
}

// ---------------- 64x128-tile GEMM variant for small-grid shapes ----------
template <bool OUTB, bool SILU, bool RES>
__global__ __launch_bounds__(256, 4) void gemm_bt64_kernel(
    const u16* __restrict__ A, const u16* __restrict__ W,
    const float* __restrict__ bias, const float* __restrict__ res,
    void* __restrict__ out, int N, int K, int nx) {
  __shared__ __align__(16) u16 As[2 * 64 * 32];   // 8KB
  __shared__ __align__(16) u16 Bs[2 * 128 * 32];  // 16KB
  int t = threadIdx.x;
  int lane = t & 63, wave = t >> 6;
  int l15 = lane & 15, quad = lane >> 4;
  int nblk = gridDim.x;
  int L = (blockIdx.x & 7) * (nblk >> 3) + (blockIdx.x >> 3);
  int rowBlk = (L / nx) * 64, colBlk = (L % nx) * 128;
  const u16* Ag = A + (size_t)(rowBlk + (t >> 2)) * K + (t & 3) * 8;
  const u16* Wg = W + (size_t)(colBlk + (t >> 2)) * K + (t & 3) * 8;
  u16* AsW = As + wave * 512;
  u16* BsW = Bs + wave * 512;
  int brow = wave * 32;
  floatx4 acc[4][2] = {};
  for (int k0 = 0; k0 < K; k0 += 64) {
    gll16(Ag + k0, AsW);
    gll16(Ag + k0 + 32, AsW + 2048);
    gll16(Wg + k0, BsW);
    gll16(Wg + (size_t)64 * K + k0, BsW + 2048);
    gll16(Wg + k0 + 32, BsW + 4096);
    gll16(Wg + (size_t)64 * K + k0 + 32, BsW + 6144);
    __syncthreads();
#pragma unroll 1
    for (int kk = 0; kk < 2; ++kk) {
      short8 a[4], b[2];
#pragma unroll
      for (int i = 0; i < 4; ++i)
        a[i] = *(const short8*)(As + kk * 2048 +
                                (size_t)(i * 16 + l15) * 32 + quad * 8);
#pragma unroll
      for (int j = 0; j < 2; ++j)
        b[j] = *(const short8*)(Bs + kk * 4096 +
                                (size_t)(brow + j * 16 + l15) * 32 + quad * 8);
#pragma unroll
      for (int i = 0; i < 4; ++i)
#pragma unroll
        for (int j = 0; j < 2; ++j)
          acc[i][j] = MFMA_BF16(a[i], b[j], acc[i][j]);
    }
    __syncthreads();
  }
#pragma unroll
  for (int j = 0; j < 2; ++j) {
    int col = colBlk + brow + j * 16 + l15;
    float bs = bias[col];
#pragma unroll
    for (int i = 0; i < 4; ++i) {
      int row0 = rowBlk + i * 16 + quad * 4;
#pragma unroll
      for (int r = 0; r < 4; ++r) {
        size_t idx = (size_t)(row0 + r) * N + col;
        float v = acc[i][j][r] + bs;
        if (RES) v += res[idx];
        if (SILU) v = v * (1.0f / (1.0f + __expf(-v)));
        if (OUTB) ((u16*)out)[idx] = f2bf(v);
        else ((float*)out)[idx] = v;
      }
    }
  }
}

// ---------------- attention ctx v2 + T5 setprio around MFMA clusters ------
__global__ __launch_bounds__(256, 4) void attn_ctx_kernel(const u16* __restrict__ qkv,
                                                          const u16* __restrict__ vT,
                                                          u16* __restrict__ ctx,
                                                          float* __restrict__ linv_g) {
  __shared__ __align__(16) u16 Kb[2][4096];  // [key][slot8] swizzled, 8KB
  __shared__ __align__(16) u16 Vb[2][4096];  // [dh ][slot8] swizzled, 8KB
  int t = threadIdx.x, lane = t & 63, wave = t >> 6;
  int l31 = lane & 31, hi = lane >> 5;
  int li = lane >> 3, sl = lane & 7;  // staging: row r0+li, slot sl
  int bid = blockIdx.x;
  int L = (bid & 7) * 128 + (bid >> 3);
  int qblk = L & 7, h = (L >> 3) & 7, b = L >> 6;
  int q0w = qblk * 128 + wave * 32;

  short8 qf[4];
  const u16* qbase = qkv + (size_t)(b * 1024 + q0w + l31) * 1536 + h * 64;
#pragma unroll
  for (int t4 = 0; t4 < 4; ++t4)
    qf[t4] = *(const short8*)(qbase + t4 * 16 + hi * 8);

  short8 ones;
#pragma unroll
  for (int i = 0; i < 8; ++i) ones[i] = (short)0x3F80;  // bf16 1.0

  floatx16 oacc[2] = {};
  floatx16 psum = {};

  const u16* ksec = qkv + (size_t)(b * 1024) * 1536 + 512 + h * 64;  // + key*1536
  const u16* vsec = vT + ((size_t)(b * 8 + h) * 64) * 1024;          // + dh*1024

  auto stageKV = [&](int c, u16* kbuf, u16* vbuf) {
#pragma unroll
    for (int j = 0; j < 2; ++j) {
      int r0 = wave * 16 + j * 8;
      int row = r0 + li;
      gll16(ksec + (size_t)(c * 64 + row) * 1536 + ((sl ^ (row & 7)) << 3),
            kbuf + r0 * 64);
      gll16(vsec + (size_t)row * 1024 + c * 64 + ((sl ^ (row & 7)) << 3),
            vbuf + r0 * 64);
    }
  };

  stageKV(0, Kb[0], Vb[0]);
  __syncthreads();

#pragma unroll 1
  for (int c = 0; c < 16; ++c) {
    int bf = c & 1;
    if (c < 15) stageKV(c + 1, Kb[bf ^ 1], Vb[bf ^ 1]);
    short8 pa[4];
#pragma unroll
    for (int ct = 0; ct < 2; ++ct) {
      floatx16 s = {};
      __builtin_amdgcn_s_setprio(1);
#pragma unroll
      for (int t4 = 0; t4 < 4; ++t4) {
        int key = ct * 32 + l31;
        int g2 = t4 * 2 + hi;
        short8 kf = *(const short8*)&Kb[bf][key * 64 + ((g2 ^ (key & 7)) << 3)];
        s = MFMA32(kf, qf[t4], s);
      }
      __builtin_amdgcn_s_setprio(0);
#pragma unroll
      for (int r = 0; r < 16; ++r) s[r] = fexp8(s[r]);
#pragma unroll
      for (int j = 0; j < 2; ++j) {
        unsigned a0 = cvtpk(s[j * 8 + 0], s[j * 8 + 1]);
        unsigned b0 = cvtpk(s[j * 8 + 4], s[j * 8 + 5]);
        unsigned a1 = cvtpk(s[j * 8 + 2], s[j * 8 + 3]);
        unsigned b1 = cvtpk(s[j * 8 + 6], s[j * 8 + 7]);
        plswap(a0, b0);
        plswap(a1, b1);
        union { unsigned u[4]; short8 v8; } uu;
        uu.u[0] = a0; uu.u[1] = a1; uu.u[2] = b0; uu.u[3] = b1;
        pa[ct * 2 + j] = uu.v8;
      }
    }
    __builtin_amdgcn_s_setprio(1);
#pragma unroll
    for (int ks = 0; ks < 4; ++ks) {
      psum = MFMA32(pa[ks], ones, psum);  // rowsum in oacc layout
#pragma unroll
      for (int ct2 = 0; ct2 < 2; ++ct2) {
        int dh = ct2 * 32 + l31;
        int kg = ks * 2 + hi;
        short8 vf = *(const short8*)&Vb[bf][dh * 64 + ((kg ^ (dh & 7)) << 3)];
        oacc[ct2] = MFMA32(pa[ks], vf, oacc[ct2]);
      }
    }
    __builtin_amdgcn_s_setprio(0);
    __syncthreads();
  }

  float il[16];
#pragma unroll
  for (int r = 0; r < 16; ++r) il[r] = 1.0f / psum[r];
  if (l31 == 0) {
#pragma unroll
    for (int reg = 0; reg < 16; ++reg) {
      int row = (reg & 3) + 8 * (reg >> 2) + 4 * hi;
      linv_g[(size_t)(b * 8 + h) * 1024 + q0w + row] = il[reg];
    }
  }
#pragma unroll
  for (int ct = 0; ct < 2; ++ct)
#pragma unroll
    for (int reg = 0; reg < 16; ++reg) {
      int row = (reg & 3) + 8 * (reg >> 2) + 4 * hi;
      ctx[(size_t)(b * 1024 + q0w + row) * 512 + h * 64 + ct * 32 + l31] =
          f2bf(oacc[ct][reg] * il[reg]);
    }
}

// ---------------- averaged attention weights v8 (proven config) -----------
__global__ __launch_bounds__(256, 4) void attn_avg_kernel(const u16* __restrict__ qkv,
                                                          const float* __restrict__ linv_g,
                                                          float* __restrict__ attnw) {
  __shared__ __align__(16) u16 Qs[128 * 64];  // [qrow][slot8x u16] 16KB
  __shared__ __align__(16) u16 Ks[64 * 64];   // [key ][slot8x u16]  8KB
  int t = threadIdx.x, lane = t & 63, wave = t >> 6;
  int l31 = lane & 31, hi = lane >> 5;
  int bid = blockIdx.x;
  // 2048 blocks; XCD k (= bid%8) owns L in [256k, 256k+256) = batches {2k,2k+1}
  int L = (bid & 7) * 256 + (bid >> 3);
  int b = L >> 7;
  int r7 = L & 127;
  int kq = r7 & 15, qb = r7 >> 4;
  int q0 = qb * 128;
  int q0w = q0 + wave * 32;
  int key0 = kq * 64;

  int li = lane >> 3, sl = lane & 7;  // staging: lane covers row r0+li, slot sl

  floatx16 acc0 = {}, acc1 = {};

#pragma unroll 1
  for (int h = 0; h < 8; ++h) {
    // ---- stage Q[h] (16 gll16, 4/wave) and K[h] (8 gll16, 2/wave), coalesced
    {
      const u16* qsec = qkv + (size_t)(b * 1024 + q0) * 1536 + h * 64;
#pragma unroll
      for (int j = 0; j < 4; ++j) {
        int r0 = wave * 32 + j * 8;
        int row = r0 + li;
        gll16(qsec + (size_t)row * 1536 + ((sl ^ (row & 7)) << 3), Qs + r0 * 64);
      }
      const u16* ksec = qkv + (size_t)(b * 1024 + key0) * 1536 + 512 + h * 64;
#pragma unroll
      for (int j = 0; j < 2; ++j) {
        int r0 = wave * 16 + j * 8;
        int row = r0 + li;
        gll16(ksec + (size_t)row * 1536 + ((sl ^ (row & 7)) << 3), Ks + r0 * 64);
      }
    }
    __syncthreads();  // staged data landed (vmcnt drain folded into barrier)

    // linv: broadcast loads (uniform over l31, 2 lines/instr)
    const float* lg = linv_g + (size_t)(b * 8 + h) * 1024 + q0w + 4 * hi;
    float4 il0 = *(const float4*)(lg);
    float4 il1 = *(const float4*)(lg + 8);
    float4 il2 = *(const float4*)(lg + 16);
    float4 il3 = *(const float4*)(lg + 24);
    float il[16] = {il0.x, il0.y, il0.z, il0.w, il1.x, il1.y, il1.z, il1.w,
                    il2.x, il2.y, il2.z, il2.w, il3.x, il3.y, il3.z, il3.w};

    // Q fragments from LDS (swizzled read)
    short8 qf[4];
#pragma unroll
    for (int t4 = 0; t4 < 4; ++t4) {
      int row = wave * 32 + l31;
      int g2 = t4 * 2 + hi;
      qf[t4] = *(const short8*)(Qs + row * 64 + ((g2 ^ (row & 7)) << 3));
    }
#pragma unroll
    for (int ct = 0; ct < 2; ++ct) {
      floatx16 sacc = {};
#pragma unroll
      for (int t4 = 0; t4 < 4; ++t4) {
        int key = ct * 32 + l31;
        int g2 = t4 * 2 + hi;
        short8 kf = *(const short8*)(Ks + key * 64 + ((g2 ^ (key & 7)) << 3));
        sacc = MFMA32(qf[t4], kf, sacc);
      }
      if (ct == 0) {
#pragma unroll
        for (int r = 0; r < 16; ++r) acc0[r] += fexp8(sacc[r]) * il[r];
      } else {
#pragma unroll
        for (int r = 0; r < 16; ++r) acc1[r] += fexp8(sacc[r]) * il[r];
      }
    }
    __syncthreads();  // all waves done reading before next h restage
  }

#pragma unroll
  for (int r = 0; r < 16; ++r) {
    int row = (r & 3) + 8 * (r >> 2) + 4 * hi;
    float* dst = &attnw[(size_t)(b * 1024 + q0w + row) * 1024 + key0 + l31];
    __builtin_nontemporal_store(acc0[r] * 0.125f, dst);
    __builtin_nontemporal_store(acc1[r] * 0.125f, dst + 32);
  }
}

// ---------------- host launch ----------------
extern "C" void kernel_launch(void* const* d_in, const int* in_sizes, int n_in,
                              void* d_out, int out_size, void* d_ws, size_t ws_size,
                              hipStream_t stream) {
  (void)in_sizes; (void)n_in; (void)out_size; (void)ws_size;
  const float* h   = (const float*)d_in[0];
  const float* g1  = (const float*)d_in[1];
  const float* be1 = (const float*)d_in[2];
  const float* wq  = (const float*)d_in[3];
  const float* bq  = (const float*)d_in[4];
  const float* wk  = (const float*)d_in[5];
  const float* bk  = (const float*)d_in[6];
  const float* wv  = (const float*)d_in[7];
  const float* bv  = (const float*)d_in[8];
  const float* wo  = (const float*)d_in[9];
  const float* bo  = (const float*)d_in[10];
  const float* g2  = (const float*)d_in[11];
  const float* be2 = (const float*)d_in[12];
  const float* w1  = (const float*)d_in[13];
  const float* b1  = (const float*)d_in[14];
  const float* w2  = (const float*)d_in[15];
  const float* b2  = (const float*)d_in[16];

  char* p = (char*)d_ws;
  auto carve = [&](size_t bytes) {
    char* r = p;
    p += (bytes + 255) & ~(size_t)255;
    return r;
  };
  u16*   wcat = (u16*)carve((size_t)1536 * 512 * 2);
  u16*   wob  = (u16*)carve((size_t)512 * 512 * 2);
  u16*   w1b  = (u16*)carve((size_t)1024 * 512 * 2);
  u16*   w2b  = (u16*)carve((size_t)512 * 1024 * 2);
  float* bcat = (float*)carve((size_t)1536 * 4);
  u16*   hn   = (u16*)carve((size_t)16384 * 512 * 2);
  u16*   qkvb = (u16*)carve((size_t)16384 * 1536 * 2);
  u16*   vTb  = (u16*)carve((size_t)16384 * 512 * 2);
  u16*   ctxb = (u16*)carve((size_t)16384 * 512 * 2);
  u16*   fb   = (u16*)carve((size_t)16384 * 512 * 2);
  u16*   gb   = (u16*)carve((size_t)16384 * 1024 * 2);
  float* linv = (float*)carve((size_t)16 * 8 * 1024 * 4);

  float* outh = (float*)d_out;
  float* outattn = outh + (size_t)16384 * 512;

  cast_all_kernel<<<2048, 256, 0, stream>>>(wq, wk, wv, wo, w1, w2,
                                            wcat, wob, w1b, w2b);
  bias_cat_kernel<<<6, 256, 0, stream>>>(bq, bk, bv, bcat);

  ln_kernel<<<4096, 256, 0, stream>>>(h, g1, be1, hn);
  gemm_bt_kernel<true, false, false, true><<<1536, 256, 0, stream>>>(
      hn, wcat, bcat, nullptr, qkvb, vTb, 1536, 512, 12);
  attn_ctx_kernel<<<1024, 256, 0, stream>>>(qkvb, vTb, ctxb, linv);
  attn_avg_kernel<<<2048, 256, 0, stream>>>(qkvb, linv, outattn);
  gemm_bt64_kernel<false, false, true><<<1024, 256, 0, stream>>>(
      ctxb, wob, bo, h, outh, 512, 512, 4);
  ln_kernel<<<4096, 256, 0, stream>>>(outh, g2, be2, fb);
  gemm_bt_kernel<true, true, false, false><<<1024, 256, 0, stream>>>(
      fb, w1b, b1, nullptr, gb, nullptr, 1024, 512, 8);
  gemm_bt64_kernel<false, false, true><<<1024, 256, 0, stream>>>(
      gb, w2b, b2, outh, outh, 512, 1024, 4);
}